// Round 11
// baseline (191.327 us; speedup 1.0000x reference)
//
#include <hip/hip_runtime.h>
#include <hip/hip_bf16.h>

#define BB 8
#define TT 2048
#define DD 512
#define SQRTD 22.62741699796952f

typedef float fv4 __attribute__((ext_vector_type(4)));
typedef short bv8 __attribute__((ext_vector_type(8)));
typedef short bv4 __attribute__((ext_vector_type(4)));

__device__ __forceinline__ short f2bf(float f) {
  __hip_bfloat16 h = __float2bfloat16(f);
  return *reinterpret_cast<short*>(&h);
}
__device__ __forceinline__ float bf2f(short s) {
  union { unsigned u; float f; } a; a.u = ((unsigned)(unsigned short)s) << 16;
  return a.f;
}

__device__ __forceinline__ void gld_lds16(const void* g, void* l) {
  __builtin_amdgcn_global_load_lds(
      (const __attribute__((address_space(1))) void*)g,
      (__attribute__((address_space(3))) void*)l, 16, 0, 0);
}

// ---------------- K0: cast W (f32 512x512 x3) -> bf16
__global__ __launch_bounds__(256) void k_castw(
    const float* __restrict__ Wq, const float* __restrict__ Wk,
    const float* __restrict__ Wv, short* __restrict__ Wb)
{
  const int z = blockIdx.y;
  const float* __restrict__ src = (z == 0) ? Wq : (z == 1) ? Wk : Wv;
  short* __restrict__ dst = Wb + (size_t)z * DD * DD;
  int i = blockIdx.x * 256 + threadIdx.x;          // 8 elems per thread
  fv4 a = ((const fv4*)src)[i * 2];
  fv4 b = ((const fv4*)src)[i * 2 + 1];
  bv8 h;
  #pragma unroll
  for (int e = 0; e < 4; ++e) { h[e] = f2bf(a[e]); h[4 + e] = f2bf(b[e]); }
  ((bv8*)dst)[i] = h;
}

// ---------------- K1: projection GEMM: C = X @ W^T (X f32, W bf16, C bf16)
// Tile 128m x 256n, BK=64, 512 thr / 8 waves (2M x 4N, wave = 64x64).
// z==2 (V): epilogue writes Vt[b][d][t] directly via swizzled LDS bounce.
__global__ __launch_bounds__(512, 4) void k_proj2(
    const float* __restrict__ Xq, const float* __restrict__ Xk, const float* __restrict__ Xv,
    const short* __restrict__ Wb,
    short* __restrict__ Qb, short* __restrict__ Kb, short* __restrict__ Vt)
{
  __shared__ __align__(16) char ShM[49152];   // Xs 16KB | Ws 32KB ; epi: Tb 32KB
  short* Xs = (short*)ShM;
  short* Ws = (short*)(ShM + 16384);
  const int z = blockIdx.z;
  const float* __restrict__ X = (z == 0) ? Xq : (z == 1) ? Xk : Xv;
  const short* __restrict__ W = Wb + (size_t)z * DD * DD;
  const int m0 = blockIdx.x * 128;
  const int n0 = blockIdx.y * 256;
  const int t = threadIdx.x;
  const int lane = t & 63;
  const int w = t >> 6;
  const int wr = (w >> 2) * 64, wc = (w & 3) * 64;
  const int l15 = lane & 15, l4 = lane >> 4;
  fv4 acc[4][4] = {};
  for (int kt = 0; kt < DD; kt += 64) {
    #pragma unroll
    for (int j = 0; j < 4; ++j) {
      int f = j * 512 + t;
      int row = f >> 3, c8 = f & 7;
      gld_lds16(W + (size_t)(n0 + row) * DD + kt + ((c8 ^ (row & 7)) << 3),
                Ws + (size_t)f * 8);
    }
    #pragma unroll
    for (int j = 0; j < 4; ++j) {
      int f = j * 512 + t;
      int row = f >> 4, c4 = f & 15;
      fv4 va = *(const fv4*)(X + (size_t)(m0 + row) * DD + kt + c4 * 4);
      bv4 ha;
      #pragma unroll
      for (int e = 0; e < 4; ++e) ha[e] = f2bf(va[e]);
      *(bv4*)((char*)Xs + ((row * 128 + c4 * 8) ^ ((row & 7) << 4))) = ha;
    }
    __syncthreads();
    #pragma unroll
    for (int ks = 0; ks < 2; ++ks) {
      bv8 af[4], bfr[4];
      #pragma unroll
      for (int i = 0; i < 4; ++i) {
        int ra = wr + i * 16 + l15;
        af[i] = *(bv8*)((char*)Xs + ((ra * 128 + ks * 64 + l4 * 16) ^ ((ra & 7) << 4)));
        int rb = wc + i * 16 + l15;
        bfr[i] = *(bv8*)((char*)Ws + ((rb * 128 + ks * 64 + l4 * 16) ^ ((rb & 7) << 4)));
      }
      #pragma unroll
      for (int mi = 0; mi < 4; ++mi)
        #pragma unroll
        for (int ni = 0; ni < 4; ++ni)
          acc[mi][ni] = __builtin_amdgcn_mfma_f32_16x16x32_bf16(af[mi], bfr[ni], acc[mi][ni], 0, 0, 0);
    }
    __syncthreads();
  }
  if (z != 2) {
    short* __restrict__ C = (z == 0) ? Qb : Kb;
    #pragma unroll
    for (int mi = 0; mi < 4; ++mi)
      #pragma unroll
      for (int r = 0; r < 4; ++r) {
        int gm = m0 + wr + mi * 16 + (l4 << 2) + r;
        #pragma unroll
        for (int ni = 0; ni < 4; ++ni) {
          int gn = n0 + wc + ni * 16 + l15;
          C[(size_t)gm * DD + gn] = f2bf(acc[mi][ni][r]);
        }
      }
  } else {
    // V: write transposed Vt[b][d][t] via LDS bounce, two 128-d halves
    const int b2 = m0 >> 11, t0l = m0 & (TT - 1);
    short* Tb = (short*)ShM;   // [128 d][128 t], swizzled 256B rows
    #pragma unroll
    for (int hd = 0; hd < 2; ++hd) {
      if ((wc >> 7) == hd) {
        #pragma unroll
        for (int mi = 0; mi < 4; ++mi)
          #pragma unroll
          for (int r = 0; r < 4; ++r) {
            int tl = wr + mi * 16 + (l4 << 2) + r;
            #pragma unroll
            for (int ni = 0; ni < 4; ++ni) {
              int dl = (wc & 127) + ni * 16 + l15;
              *(short*)((char*)Tb + ((dl * 256 + tl * 2) ^ ((dl & 7) << 4))) = f2bf(acc[mi][ni][r]);
            }
          }
      }
      __syncthreads();
      #pragma unroll
      for (int c = 0; c < 4; ++c) {
        int f = c * 512 + t;
        int dl = f >> 4, ch = f & 15;
        bv8 v = *(const bv8*)((const char*)Tb + ((dl * 256 + ch * 16) ^ ((dl & 7) << 4)));
        *(bv8*)(Vt + ((size_t)b2 * DD + n0 + hd * 128 + dl) * TT + t0l + ch * 8) = v;
      }
      __syncthreads();
    }
  }
}

// ---------------- K2: S-GEMM with fused softmax-numerator epilogue.
// P = exp(sqrtD*QK^T + mask); also writes per-k-tile rowsum partials Lpart.
// Tile 128x128, K=512, 4 waves. Mask prefetched to 64 regs at kernel start.
__global__ __launch_bounds__(256, 2) void k_sgemm(
    const short* __restrict__ Qb, const short* __restrict__ Kb,
    const float* __restrict__ mask, short* __restrict__ Pq,
    float* __restrict__ Lpart)
{
  __shared__ __align__(16) short Sh[2][128 * 64];  // At | Bt ; epilogue: Ps
  short* At = Sh[0];
  short* Bt = Sh[1];
  const int b = blockIdx.z;
  const int m0 = blockIdx.x * 128;   // q rows
  const int ky = blockIdx.y;         // k-tile index
  const int n0 = ky * 128;           // k cols
  const int t = threadIdx.x;
  const int lane = t & 63;
  const int w = t >> 6;
  const int wr = (w >> 1) * 64, wc = (w & 1) * 64;
  const int l15 = lane & 15, l4 = lane >> 4;

  // ---- prefetch mask tile values for this thread's 64 outputs (hidden by k-loop)
  float mk[4][4][4];   // [mi][r][ni]
  #pragma unroll
  for (int mi = 0; mi < 4; ++mi)
    #pragma unroll
    for (int r = 0; r < 4; ++r) {
      int row = wr + mi * 16 + (l4 << 2) + r;
      const float* mrow = mask + ((size_t)b * TT + m0 + row) * TT + n0;
      #pragma unroll
      for (int ni = 0; ni < 4; ++ni)
        mk[mi][r][ni] = mrow[wc + ni * 16 + l15];
    }
  __builtin_amdgcn_sched_barrier(0);

  fv4 acc[4][4] = {};
  for (int kt = 0; kt < DD; kt += 64) {
    #pragma unroll
    for (int j = 0; j < 4; ++j) {
      int f = j * 256 + t;
      int row = f >> 3, c8 = f & 7;
      int byte = (row * 128 + c8 * 16) ^ ((row & 7) << 4);
      bv8 va = *(const bv8*)(Qb + ((size_t)b * TT + m0 + row) * DD + kt + c8 * 8);
      *(bv8*)((char*)At + byte) = va;
      bv8 vb = *(const bv8*)(Kb + ((size_t)b * TT + n0 + row) * DD + kt + c8 * 8);
      *(bv8*)((char*)Bt + byte) = vb;
    }
    __syncthreads();
    #pragma unroll
    for (int ks = 0; ks < 2; ++ks) {
      bv8 af[4], bfr[4];
      #pragma unroll
      for (int i = 0; i < 4; ++i) {
        int ra = wr + i * 16 + l15;
        af[i] = *(bv8*)((char*)At + ((ra * 128 + ks * 64 + (l4 * 16)) ^ ((ra & 7) << 4)));
        int rb = wc + i * 16 + l15;
        bfr[i] = *(bv8*)((char*)Bt + ((rb * 128 + ks * 64 + (l4 * 16)) ^ ((rb & 7) << 4)));
      }
      #pragma unroll
      for (int mi = 0; mi < 4; ++mi)
        #pragma unroll
        for (int ni = 0; ni < 4; ++ni)
          acc[mi][ni] = __builtin_amdgcn_mfma_f32_16x16x32_bf16(af[mi], bfr[ni], acc[mi][ni], 0, 0, 0);
    }
    __syncthreads();
  }
  // epilogue: scale + mask + exp -> Ps (swizzled 256B rows)
  short* Ps = &Sh[0][0];   // 128 rows x 256 B = 32 KB
  #pragma unroll
  for (int mi = 0; mi < 4; ++mi)
    #pragma unroll
    for (int r = 0; r < 4; ++r) {
      int row = wr + mi * 16 + (l4 << 2) + r;
      #pragma unroll
      for (int ni = 0; ni < 4; ++ni) {
        int col = wc + ni * 16 + l15;
        float sx = acc[mi][ni][r] * SQRTD + mk[mi][r][ni];
        *(short*)((char*)Ps + ((row * 256 + col * 2) ^ ((row & 7) << 4))) = f2bf(__expf(sx));
      }
    }
  __syncthreads();
  // store pass + per-row partial sums (deterministic, from the bf16 P itself)
  #pragma unroll
  for (int c = 0; c < 8; ++c) {
    int f = c * 256 + t;
    int row = f >> 4, ch = f & 15;
    bv8 v = *(const bv8*)((const char*)Ps + ((row * 256 + ch * 16) ^ ((row & 7) << 4)));
    *(bv8*)(Pq + ((size_t)b * TT + m0 + row) * TT + n0 + ch * 8) = v;
    float s8 = 0.f;
    #pragma unroll
    for (int e = 0; e < 8; ++e) s8 += bf2f(v[e]);
    s8 += __shfl_xor(s8, 1);
    s8 += __shfl_xor(s8, 2);
    s8 += __shfl_xor(s8, 4);
    s8 += __shfl_xor(s8, 8);
    if (ch == 0)
      Lpart[(size_t)ky * (BB * TT) + (size_t)b * TT + m0 + row] = s8;
  }
}

// ---------------- K3: O = (P @ Vt^T) / l.  Tile 128x128, K = 2048.
// l read from Lpart partials (summed once into LDS at block start).
__global__ __launch_bounds__(256, 3) void k_pv(
    const short* __restrict__ P, const short* __restrict__ Vt,
    const float* __restrict__ Lpart, float* __restrict__ Out)
{
  __shared__ __align__(16) short At[128 * 64];
  __shared__ __align__(16) short Bt[128 * 64];
  __shared__ float Lrow[128];
  const int b = blockIdx.z;
  const int m0 = blockIdx.x * 128;
  const int n0 = blockIdx.y * 128;
  const int t = threadIdx.x;
  const int lane = t & 63;
  const int w = t >> 6;
  const int wr = (w >> 1) * 64, wc = (w & 1) * 64;
  const int l15 = lane & 15, l4 = lane >> 4;
  if (t < 128) {
    float s = 0.f;
    #pragma unroll
    for (int ky = 0; ky < 16; ++ky)
      s += Lpart[(size_t)ky * (BB * TT) + (size_t)b * TT + m0 + t];
    Lrow[t] = s;
  }
  fv4 acc[4][4] = {};
  for (int kt = 0; kt < TT; kt += 64) {
    #pragma unroll
    for (int j = 0; j < 4; ++j) {
      int f = j * 256 + t;
      int row = f >> 3, c8 = f & 7;
      int byte = (row * 128 + c8 * 16) ^ ((row & 7) << 4);
      bv8 va = *(const bv8*)(P + ((size_t)b * TT + m0 + row) * TT + kt + c8 * 8);
      *(bv8*)((char*)At + byte) = va;
      bv8 vb = *(const bv8*)(Vt + ((size_t)b * DD + n0 + row) * TT + kt + c8 * 8);
      *(bv8*)((char*)Bt + byte) = vb;
    }
    __syncthreads();
    #pragma unroll
    for (int ks = 0; ks < 2; ++ks) {
      bv8 af[4], bfr[4];
      #pragma unroll
      for (int i = 0; i < 4; ++i) {
        int ra = wr + i * 16 + l15;
        af[i] = *(bv8*)((char*)At + ((ra * 128 + ks * 64 + (l4 * 16)) ^ ((ra & 7) << 4)));
        int rb = wc + i * 16 + l15;
        bfr[i] = *(bv8*)((char*)Bt + ((rb * 128 + ks * 64 + (l4 * 16)) ^ ((rb & 7) << 4)));
      }
      #pragma unroll
      for (int mi = 0; mi < 4; ++mi)
        #pragma unroll
        for (int ni = 0; ni < 4; ++ni)
          acc[mi][ni] = __builtin_amdgcn_mfma_f32_16x16x32_bf16(af[mi], bfr[ni], acc[mi][ni], 0, 0, 0);
    }
    __syncthreads();
  }
  #pragma unroll
  for (int mi = 0; mi < 4; ++mi)
    #pragma unroll
    for (int r = 0; r < 4; ++r) {
      int ml = wr + mi * 16 + (l4 << 2) + r;
      int gm = m0 + ml;
      float inv = 1.0f / Lrow[ml];
      #pragma unroll
      for (int ni = 0; ni < 4; ++ni) {
        int gn = n0 + wc + ni * 16 + l15;
        Out[((size_t)b * TT + gm) * DD + gn] = acc[mi][ni][r] * inv;
      }
    }
}

extern "C" void kernel_launch(void* const* d_in, const int* in_sizes, int n_in,
                              void* d_out, int out_size, void* d_ws, size_t ws_size,
                              hipStream_t stream) {
  const float* ft_q = (const float*)d_in[0];
  const float* ft_k = (const float*)d_in[1];
  const float* ft_v = (const float*)d_in[2];
  const float* mask = (const float*)d_in[3];
  const float* Wq   = (const float*)d_in[4];
  const float* Wk   = (const float*)d_in[5];
  const float* Wv   = (const float*)d_in[6];
  float* Out = (float*)d_out;

  const size_t nBTD = (size_t)BB * TT * DD;   // 8,388,608
  const size_t nBTT = (size_t)BB * TT * TT;   // 33,554,432
  short* Qb = (short*)d_ws;
  short* Kb = Qb + nBTD;
  short* Vt = Kb + nBTD;
  short* Pq = Vt + nBTD;
  short* Wb = Pq + nBTT;                      // 3 x 512 x 512 bf16
  float* Lpart = (float*)(Wb + (size_t)3 * DD * DD);  // [16][B*T]

  k_castw<<<dim3(DD * DD / 8 / 256, 3), 256, 0, stream>>>(Wq, Wk, Wv, Wb);
  k_proj2<<<dim3(TT * BB / 128, DD / 256, 3), 512, 0, stream>>>(ft_q, ft_k, ft_v, Wb, Qb, Kb, Vt);
  k_sgemm<<<dim3(TT / 128, TT / 128, BB), 256, 0, stream>>>(Qb, Kb, mask, Pq, Lpart);
  k_pv<<<dim3(TT / 128, DD / 128, BB), 256, 0, stream>>>(Pq, Vt, Lpart, Out);
}

// Round 12
// 188.394 us; speedup vs baseline: 1.0156x; 1.0156x over previous
//
#include <hip/hip_runtime.h>
#include <hip/hip_bf16.h>

#define BB 8
#define TT 2048
#define DD 512
#define SQRTD 22.62741699796952f

typedef float fv4 __attribute__((ext_vector_type(4)));
typedef short bv8 __attribute__((ext_vector_type(8)));
typedef short bv4 __attribute__((ext_vector_type(4)));

__device__ __forceinline__ short f2bf(float f) {
  __hip_bfloat16 h = __float2bfloat16(f);
  return *reinterpret_cast<short*>(&h);
}
__device__ __forceinline__ float bf2f(short s) {
  union { unsigned u; float f; } a; a.u = ((unsigned)(unsigned short)s) << 16;
  return a.f;
}

__device__ __forceinline__ void gld_lds16(const void* g, void* l) {
  __builtin_amdgcn_global_load_lds(
      (const __attribute__((address_space(1))) void*)g,
      (__attribute__((address_space(3))) void*)l, 16, 0, 0);
}

// ---------------- K0: cast W (f32 512x512 x3) -> bf16
__global__ __launch_bounds__(256) void k_castw(
    const float* __restrict__ Wq, const float* __restrict__ Wk,
    const float* __restrict__ Wv, short* __restrict__ Wb)
{
  const int z = blockIdx.y;
  const float* __restrict__ src = (z == 0) ? Wq : (z == 1) ? Wk : Wv;
  short* __restrict__ dst = Wb + (size_t)z * DD * DD;
  int i = blockIdx.x * 256 + threadIdx.x;          // 8 elems per thread
  fv4 a = ((const fv4*)src)[i * 2];
  fv4 b = ((const fv4*)src)[i * 2 + 1];
  bv8 h;
  #pragma unroll
  for (int e = 0; e < 4; ++e) { h[e] = f2bf(a[e]); h[4 + e] = f2bf(b[e]); }
  ((bv8*)dst)[i] = h;
}

// ---------------- K1: projection GEMM: C = X @ W^T (X f32, W bf16, C bf16)
// Tile 128m x 256n, BK=64, 512 thr / 8 waves (2M x 4N, wave = 64x64).
// z==2 (V): epilogue writes Vt[b][d][t] directly via swizzled LDS bounce.
__global__ __launch_bounds__(512, 4) void k_proj2(
    const float* __restrict__ Xq, const float* __restrict__ Xk, const float* __restrict__ Xv,
    const short* __restrict__ Wb,
    short* __restrict__ Qb, short* __restrict__ Kb, short* __restrict__ Vt)
{
  __shared__ __align__(16) char ShM[49152];   // Xs 16KB | Ws 32KB ; epi: Tb 32KB
  short* Xs = (short*)ShM;
  short* Ws = (short*)(ShM + 16384);
  const int z = blockIdx.z;
  const float* __restrict__ X = (z == 0) ? Xq : (z == 1) ? Xk : Xv;
  const short* __restrict__ W = Wb + (size_t)z * DD * DD;
  const int m0 = blockIdx.x * 128;
  const int n0 = blockIdx.y * 256;
  const int t = threadIdx.x;
  const int lane = t & 63;
  const int w = t >> 6;
  const int wr = (w >> 2) * 64, wc = (w & 3) * 64;
  const int l15 = lane & 15, l4 = lane >> 4;
  fv4 acc[4][4] = {};
  for (int kt = 0; kt < DD; kt += 64) {
    #pragma unroll
    for (int j = 0; j < 4; ++j) {
      int f = j * 512 + t;
      int row = f >> 3, c8 = f & 7;
      gld_lds16(W + (size_t)(n0 + row) * DD + kt + ((c8 ^ (row & 7)) << 3),
                Ws + (size_t)f * 8);
    }
    #pragma unroll
    for (int j = 0; j < 4; ++j) {
      int f = j * 512 + t;
      int row = f >> 4, c4 = f & 15;
      fv4 va = *(const fv4*)(X + (size_t)(m0 + row) * DD + kt + c4 * 4);
      bv4 ha;
      #pragma unroll
      for (int e = 0; e < 4; ++e) ha[e] = f2bf(va[e]);
      *(bv4*)((char*)Xs + ((row * 128 + c4 * 8) ^ ((row & 7) << 4))) = ha;
    }
    __syncthreads();
    #pragma unroll
    for (int ks = 0; ks < 2; ++ks) {
      bv8 af[4], bfr[4];
      #pragma unroll
      for (int i = 0; i < 4; ++i) {
        int ra = wr + i * 16 + l15;
        af[i] = *(bv8*)((char*)Xs + ((ra * 128 + ks * 64 + l4 * 16) ^ ((ra & 7) << 4)));
        int rb = wc + i * 16 + l15;
        bfr[i] = *(bv8*)((char*)Ws + ((rb * 128 + ks * 64 + l4 * 16) ^ ((rb & 7) << 4)));
      }
      #pragma unroll
      for (int mi = 0; mi < 4; ++mi)
        #pragma unroll
        for (int ni = 0; ni < 4; ++ni)
          acc[mi][ni] = __builtin_amdgcn_mfma_f32_16x16x32_bf16(af[mi], bfr[ni], acc[mi][ni], 0, 0, 0);
    }
    __syncthreads();
  }
  if (z != 2) {
    short* __restrict__ C = (z == 0) ? Qb : Kb;
    #pragma unroll
    for (int mi = 0; mi < 4; ++mi)
      #pragma unroll
      for (int r = 0; r < 4; ++r) {
        int gm = m0 + wr + mi * 16 + (l4 << 2) + r;
        #pragma unroll
        for (int ni = 0; ni < 4; ++ni) {
          int gn = n0 + wc + ni * 16 + l15;
          C[(size_t)gm * DD + gn] = f2bf(acc[mi][ni][r]);
        }
      }
  } else {
    // V: write transposed Vt[b][d][t] via LDS bounce, two 128-d halves
    const int b2 = m0 >> 11, t0l = m0 & (TT - 1);
    short* Tb = (short*)ShM;   // [128 d][128 t], swizzled 256B rows
    #pragma unroll
    for (int hd = 0; hd < 2; ++hd) {
      if ((wc >> 7) == hd) {
        #pragma unroll
        for (int mi = 0; mi < 4; ++mi)
          #pragma unroll
          for (int r = 0; r < 4; ++r) {
            int tl = wr + mi * 16 + (l4 << 2) + r;
            #pragma unroll
            for (int ni = 0; ni < 4; ++ni) {
              int dl = (wc & 127) + ni * 16 + l15;
              *(short*)((char*)Tb + ((dl * 256 + tl * 2) ^ ((dl & 7) << 4))) = f2bf(acc[mi][ni][r]);
            }
          }
      }
      __syncthreads();
      #pragma unroll
      for (int c = 0; c < 4; ++c) {
        int f = c * 512 + t;
        int dl = f >> 4, ch = f & 15;
        bv8 v = *(const bv8*)((const char*)Tb + ((dl * 256 + ch * 16) ^ ((dl & 7) << 4)));
        *(bv8*)(Vt + ((size_t)b2 * DD + n0 + hd * 128 + dl) * TT + t0l + ch * 8) = v;
      }
      __syncthreads();
    }
  }
}

// ---------------- K2: S-GEMM with fused softmax-numerator epilogue.
// P = exp(sqrtD*QK^T + mask); rowsum partials Lpart in the store pass.
// Tile 128x128, K=512, 4 waves. Mask loaded in epilogue (round-10 form).
__global__ __launch_bounds__(256, 4) void k_sgemm(
    const short* __restrict__ Qb, const short* __restrict__ Kb,
    const float* __restrict__ mask, short* __restrict__ Pq,
    float* __restrict__ Lpart)
{
  __shared__ __align__(16) short Sh[2][128 * 64];  // At | Bt ; epilogue: Ps
  short* At = Sh[0];
  short* Bt = Sh[1];
  const int b = blockIdx.z;
  const int m0 = blockIdx.x * 128;   // q rows
  const int ky = blockIdx.y;         // k-tile index
  const int n0 = ky * 128;           // k cols
  const int t = threadIdx.x;
  const int lane = t & 63;
  const int w = t >> 6;
  const int wr = (w >> 1) * 64, wc = (w & 1) * 64;
  const int l15 = lane & 15, l4 = lane >> 4;
  fv4 acc[4][4] = {};
  for (int kt = 0; kt < DD; kt += 64) {
    #pragma unroll
    for (int j = 0; j < 4; ++j) {
      int f = j * 256 + t;
      int row = f >> 3, c8 = f & 7;
      int byte = (row * 128 + c8 * 16) ^ ((row & 7) << 4);
      bv8 va = *(const bv8*)(Qb + ((size_t)b * TT + m0 + row) * DD + kt + c8 * 8);
      *(bv8*)((char*)At + byte) = va;
      bv8 vb = *(const bv8*)(Kb + ((size_t)b * TT + n0 + row) * DD + kt + c8 * 8);
      *(bv8*)((char*)Bt + byte) = vb;
    }
    __syncthreads();
    #pragma unroll
    for (int ks = 0; ks < 2; ++ks) {
      bv8 af[4], bfr[4];
      #pragma unroll
      for (int i = 0; i < 4; ++i) {
        int ra = wr + i * 16 + l15;
        af[i] = *(bv8*)((char*)At + ((ra * 128 + ks * 64 + (l4 * 16)) ^ ((ra & 7) << 4)));
        int rb = wc + i * 16 + l15;
        bfr[i] = *(bv8*)((char*)Bt + ((rb * 128 + ks * 64 + (l4 * 16)) ^ ((rb & 7) << 4)));
      }
      #pragma unroll
      for (int mi = 0; mi < 4; ++mi)
        #pragma unroll
        for (int ni = 0; ni < 4; ++ni)
          acc[mi][ni] = __builtin_amdgcn_mfma_f32_16x16x32_bf16(af[mi], bfr[ni], acc[mi][ni], 0, 0, 0);
    }
    __syncthreads();
  }
  // epilogue: scale + mask + exp -> Ps (swizzled 256B rows)
  short* Ps = &Sh[0][0];   // 128 rows x 256 B = 32 KB
  #pragma unroll
  for (int mi = 0; mi < 4; ++mi)
    #pragma unroll
    for (int r = 0; r < 4; ++r) {
      int row = wr + mi * 16 + (l4 << 2) + r;
      const float* mrow = mask + ((size_t)b * TT + m0 + row) * TT + n0;
      #pragma unroll
      for (int ni = 0; ni < 4; ++ni) {
        int col = wc + ni * 16 + l15;
        float sx = acc[mi][ni][r] * SQRTD + mrow[col];
        *(short*)((char*)Ps + ((row * 256 + col * 2) ^ ((row & 7) << 4))) = f2bf(__expf(sx));
      }
    }
  __syncthreads();
  // store pass + per-row partial sums (deterministic, from the bf16 P itself)
  #pragma unroll
  for (int c = 0; c < 8; ++c) {
    int f = c * 256 + t;
    int row = f >> 4, ch = f & 15;
    bv8 v = *(const bv8*)((const char*)Ps + ((row * 256 + ch * 16) ^ ((row & 7) << 4)));
    *(bv8*)(Pq + ((size_t)b * TT + m0 + row) * TT + n0 + ch * 8) = v;
    float s8 = 0.f;
    #pragma unroll
    for (int e = 0; e < 8; ++e) s8 += bf2f(v[e]);
    s8 += __shfl_xor(s8, 1);
    s8 += __shfl_xor(s8, 2);
    s8 += __shfl_xor(s8, 4);
    s8 += __shfl_xor(s8, 8);
    if (ch == 0)
      Lpart[(size_t)ky * (BB * TT) + (size_t)b * TT + m0 + row] = s8;
  }
}

// ---------------- K3: O = (P @ Vt^T) / l.  Tile 128x128, K = 2048.
// l read from Lpart partials (summed once into LDS at block start).
__global__ __launch_bounds__(256, 4) void k_pv(
    const short* __restrict__ P, const short* __restrict__ Vt,
    const float* __restrict__ Lpart, float* __restrict__ Out)
{
  __shared__ __align__(16) short At[128 * 64];
  __shared__ __align__(16) short Bt[128 * 64];
  __shared__ float Lrow[128];
  const int b = blockIdx.z;
  const int m0 = blockIdx.x * 128;
  const int n0 = blockIdx.y * 128;
  const int t = threadIdx.x;
  const int lane = t & 63;
  const int w = t >> 6;
  const int wr = (w >> 1) * 64, wc = (w & 1) * 64;
  const int l15 = lane & 15, l4 = lane >> 4;
  if (t < 128) {
    float s = 0.f;
    #pragma unroll
    for (int ky = 0; ky < 16; ++ky)
      s += Lpart[(size_t)ky * (BB * TT) + (size_t)b * TT + m0 + t];
    Lrow[t] = s;
  }
  fv4 acc[4][4] = {};
  for (int kt = 0; kt < TT; kt += 64) {
    #pragma unroll
    for (int j = 0; j < 4; ++j) {
      int f = j * 256 + t;
      int row = f >> 3, c8 = f & 7;
      int byte = (row * 128 + c8 * 16) ^ ((row & 7) << 4);
      bv8 va = *(const bv8*)(P + ((size_t)b * TT + m0 + row) * TT + kt + c8 * 8);
      *(bv8*)((char*)At + byte) = va;
      bv8 vb = *(const bv8*)(Vt + ((size_t)b * DD + n0 + row) * TT + kt + c8 * 8);
      *(bv8*)((char*)Bt + byte) = vb;
    }
    __syncthreads();
    #pragma unroll
    for (int ks = 0; ks < 2; ++ks) {
      bv8 af[4], bfr[4];
      #pragma unroll
      for (int i = 0; i < 4; ++i) {
        int ra = wr + i * 16 + l15;
        af[i] = *(bv8*)((char*)At + ((ra * 128 + ks * 64 + (l4 * 16)) ^ ((ra & 7) << 4)));
        int rb = wc + i * 16 + l15;
        bfr[i] = *(bv8*)((char*)Bt + ((rb * 128 + ks * 64 + (l4 * 16)) ^ ((rb & 7) << 4)));
      }
      #pragma unroll
      for (int mi = 0; mi < 4; ++mi)
        #pragma unroll
        for (int ni = 0; ni < 4; ++ni)
          acc[mi][ni] = __builtin_amdgcn_mfma_f32_16x16x32_bf16(af[mi], bfr[ni], acc[mi][ni], 0, 0, 0);
    }
    __syncthreads();
  }
  #pragma unroll
  for (int mi = 0; mi < 4; ++mi)
    #pragma unroll
    for (int r = 0; r < 4; ++r) {
      int ml = wr + mi * 16 + (l4 << 2) + r;
      int gm = m0 + ml;
      float inv = 1.0f / Lrow[ml];
      #pragma unroll
      for (int ni = 0; ni < 4; ++ni) {
        int gn = n0 + wc + ni * 16 + l15;
        Out[((size_t)b * TT + gm) * DD + gn] = acc[mi][ni][r] * inv;
      }
    }
}

extern "C" void kernel_launch(void* const* d_in, const int* in_sizes, int n_in,
                              void* d_out, int out_size, void* d_ws, size_t ws_size,
                              hipStream_t stream) {
  const float* ft_q = (const float*)d_in[0];
  const float* ft_k = (const float*)d_in[1];
  const float* ft_v = (const float*)d_in[2];
  const float* mask = (const float*)d_in[3];
  const float* Wq   = (const float*)d_in[4];
  const float* Wk   = (const float*)d_in[5];
  const float* Wv   = (const float*)d_in[6];
  float* Out = (float*)d_out;

  const size_t nBTD = (size_t)BB * TT * DD;   // 8,388,608
  const size_t nBTT = (size_t)BB * TT * TT;   // 33,554,432
  short* Qb = (short*)d_ws;
  short* Kb = Qb + nBTD;
  short* Vt = Kb + nBTD;
  short* Pq = Vt + nBTD;
  short* Wb = Pq + nBTT;                      // 3 x 512 x 512 bf16
  float* Lpart = (float*)(Wb + (size_t)3 * DD * DD);  // [16][B*T]

  k_castw<<<dim3(DD * DD / 8 / 256, 3), 256, 0, stream>>>(Wq, Wk, Wv, Wb);
  k_proj2<<<dim3(TT * BB / 128, DD / 256, 3), 512, 0, stream>>>(ft_q, ft_k, ft_v, Wb, Qb, Kb, Vt);
  k_sgemm<<<dim3(TT / 128, TT / 128, BB), 256, 0, stream>>>(Qb, Kb, mask, Pq, Lpart);
  k_pv<<<dim3(TT / 128, DD / 128, BB), 256, 0, stream>>>(Pq, Vt, Lpart, Out);
}

// Round 13
// 176.942 us; speedup vs baseline: 1.0813x; 1.0647x over previous
//
#include <hip/hip_runtime.h>
#include <hip/hip_bf16.h>

#define BB 8
#define TT 2048
#define DD 512
#define SQRTD 22.62741699796952f

typedef float fv4 __attribute__((ext_vector_type(4)));
typedef short bv8 __attribute__((ext_vector_type(8)));
typedef short bv4 __attribute__((ext_vector_type(4)));

__device__ __forceinline__ short f2bf(float f) {
  __hip_bfloat16 h = __float2bfloat16(f);
  return *reinterpret_cast<short*>(&h);
}
__device__ __forceinline__ float bf2f(short s) {
  union { unsigned u; float f; } a; a.u = ((unsigned)(unsigned short)s) << 16;
  return a.f;
}

__device__ __forceinline__ void gld_lds16(const void* g, void* l) {
  __builtin_amdgcn_global_load_lds(
      (const __attribute__((address_space(1))) void*)g,
      (__attribute__((address_space(3))) void*)l, 16, 0, 0);
}

// ---------------- K0: cast W (f32 512x512 x3) -> bf16
__global__ __launch_bounds__(256) void k_castw(
    const float* __restrict__ Wq, const float* __restrict__ Wk,
    const float* __restrict__ Wv, short* __restrict__ Wb)
{
  const int z = blockIdx.y;
  const float* __restrict__ src = (z == 0) ? Wq : (z == 1) ? Wk : Wv;
  short* __restrict__ dst = Wb + (size_t)z * DD * DD;
  int i = blockIdx.x * 256 + threadIdx.x;          // 8 elems per thread
  fv4 a = ((const fv4*)src)[i * 2];
  fv4 b = ((const fv4*)src)[i * 2 + 1];
  bv8 h;
  #pragma unroll
  for (int e = 0; e < 4; ++e) { h[e] = f2bf(a[e]); h[4 + e] = f2bf(b[e]); }
  ((bv8*)dst)[i] = h;
}

// ---------------- K1: projection GEMM: C = X @ W^T (X f32, W bf16, C bf16)
// Tile 128m x 256n, BK=64, 512 thr / 8 waves (2M x 4N, wave = 64x64).
// z==2 (V): epilogue writes Vt[b][d][t] directly via swizzled LDS bounce.
__global__ __launch_bounds__(512, 4) void k_proj2(
    const float* __restrict__ Xq, const float* __restrict__ Xk, const float* __restrict__ Xv,
    const short* __restrict__ Wb,
    short* __restrict__ Qb, short* __restrict__ Kb, short* __restrict__ Vt)
{
  __shared__ __align__(16) char ShM[49152];   // Xs 16KB | Ws 32KB ; epi: Tb 32KB
  short* Xs = (short*)ShM;
  short* Ws = (short*)(ShM + 16384);
  const int z = blockIdx.z;
  const float* __restrict__ X = (z == 0) ? Xq : (z == 1) ? Xk : Xv;
  const short* __restrict__ W = Wb + (size_t)z * DD * DD;
  const int m0 = blockIdx.x * 128;
  const int n0 = blockIdx.y * 256;
  const int t = threadIdx.x;
  const int lane = t & 63;
  const int w = t >> 6;
  const int wr = (w >> 2) * 64, wc = (w & 3) * 64;
  const int l15 = lane & 15, l4 = lane >> 4;
  fv4 acc[4][4] = {};
  for (int kt = 0; kt < DD; kt += 64) {
    #pragma unroll
    for (int j = 0; j < 4; ++j) {
      int f = j * 512 + t;
      int row = f >> 3, c8 = f & 7;
      gld_lds16(W + (size_t)(n0 + row) * DD + kt + ((c8 ^ (row & 7)) << 3),
                Ws + (size_t)f * 8);
    }
    #pragma unroll
    for (int j = 0; j < 4; ++j) {
      int f = j * 512 + t;
      int row = f >> 4, c4 = f & 15;
      fv4 va = *(const fv4*)(X + (size_t)(m0 + row) * DD + kt + c4 * 4);
      bv4 ha;
      #pragma unroll
      for (int e = 0; e < 4; ++e) ha[e] = f2bf(va[e]);
      *(bv4*)((char*)Xs + ((row * 128 + c4 * 8) ^ ((row & 7) << 4))) = ha;
    }
    __syncthreads();
    #pragma unroll
    for (int ks = 0; ks < 2; ++ks) {
      bv8 af[4], bfr[4];
      #pragma unroll
      for (int i = 0; i < 4; ++i) {
        int ra = wr + i * 16 + l15;
        af[i] = *(bv8*)((char*)Xs + ((ra * 128 + ks * 64 + l4 * 16) ^ ((ra & 7) << 4)));
        int rb = wc + i * 16 + l15;
        bfr[i] = *(bv8*)((char*)Ws + ((rb * 128 + ks * 64 + l4 * 16) ^ ((rb & 7) << 4)));
      }
      #pragma unroll
      for (int mi = 0; mi < 4; ++mi)
        #pragma unroll
        for (int ni = 0; ni < 4; ++ni)
          acc[mi][ni] = __builtin_amdgcn_mfma_f32_16x16x32_bf16(af[mi], bfr[ni], acc[mi][ni], 0, 0, 0);
    }
    __syncthreads();
  }
  if (z != 2) {
    short* __restrict__ C = (z == 0) ? Qb : Kb;
    #pragma unroll
    for (int mi = 0; mi < 4; ++mi)
      #pragma unroll
      for (int r = 0; r < 4; ++r) {
        int gm = m0 + wr + mi * 16 + (l4 << 2) + r;
        #pragma unroll
        for (int ni = 0; ni < 4; ++ni) {
          int gn = n0 + wc + ni * 16 + l15;
          C[(size_t)gm * DD + gn] = f2bf(acc[mi][ni][r]);
        }
      }
  } else {
    // V: write transposed Vt[b][d][t] via LDS bounce, two 128-d halves
    const int b2 = m0 >> 11, t0l = m0 & (TT - 1);
    short* Tb = (short*)ShM;   // [128 d][128 t], swizzled 256B rows
    #pragma unroll
    for (int hd = 0; hd < 2; ++hd) {
      if ((wc >> 7) == hd) {
        #pragma unroll
        for (int mi = 0; mi < 4; ++mi)
          #pragma unroll
          for (int r = 0; r < 4; ++r) {
            int tl = wr + mi * 16 + (l4 << 2) + r;
            #pragma unroll
            for (int ni = 0; ni < 4; ++ni) {
              int dl = (wc & 127) + ni * 16 + l15;
              *(short*)((char*)Tb + ((dl * 256 + tl * 2) ^ ((dl & 7) << 4))) = f2bf(acc[mi][ni][r]);
            }
          }
      }
      __syncthreads();
      #pragma unroll
      for (int c = 0; c < 4; ++c) {
        int f = c * 512 + t;
        int dl = f >> 4, ch = f & 15;
        bv8 v = *(const bv8*)((const char*)Tb + ((dl * 256 + ch * 16) ^ ((dl & 7) << 4)));
        *(bv8*)(Vt + ((size_t)b2 * DD + n0 + hd * 128 + dl) * TT + t0l + ch * 8) = v;
      }
      __syncthreads();
    }
  }
}

// ---------------- K2: S-GEMM with fused softmax-numerator epilogue.
// P = exp(sqrtD*QK^T + mask); rowsum partials Lpart in the store pass.
// Tile 128x128, K=512, 4 waves. Q/K staged via global_load_lds
// (linear dest, pre-swizzled source chunk), reads XOR-swizzled.
__global__ __launch_bounds__(256, 3) void k_sgemm(
    const short* __restrict__ Qb, const short* __restrict__ Kb,
    const float* __restrict__ mask, short* __restrict__ Pq,
    float* __restrict__ Lpart)
{
  __shared__ __align__(16) short Sh[2][128 * 64];  // At | Bt ; epilogue: Ps
  short* At = Sh[0];
  short* Bt = Sh[1];
  const int b = blockIdx.z;
  const int m0 = blockIdx.x * 128;   // q rows
  const int ky = blockIdx.y;         // k-tile index
  const int n0 = ky * 128;           // k cols
  const int t = threadIdx.x;
  const int lane = t & 63;
  const int w = t >> 6;
  const int wr = (w >> 1) * 64, wc = (w & 1) * 64;
  const int l15 = lane & 15, l4 = lane >> 4;
  fv4 acc[4][4] = {};
  for (int kt = 0; kt < DD; kt += 64) {
    #pragma unroll
    for (int j = 0; j < 4; ++j) {
      int f = j * 256 + t;
      int row = f >> 3, c8 = f & 7;
      int srcc = (c8 ^ (row & 7)) << 3;
      gld_lds16(Qb + ((size_t)b * TT + m0 + row) * DD + kt + srcc, (char*)At + (size_t)f * 16);
      gld_lds16(Kb + ((size_t)b * TT + n0 + row) * DD + kt + srcc, (char*)Bt + (size_t)f * 16);
    }
    __syncthreads();
    #pragma unroll
    for (int ks = 0; ks < 2; ++ks) {
      bv8 af[4], bfr[4];
      #pragma unroll
      for (int i = 0; i < 4; ++i) {
        int ra = wr + i * 16 + l15;
        af[i] = *(bv8*)((char*)At + ((ra * 128 + ks * 64 + (l4 * 16)) ^ ((ra & 7) << 4)));
        int rb = wc + i * 16 + l15;
        bfr[i] = *(bv8*)((char*)Bt + ((rb * 128 + ks * 64 + (l4 * 16)) ^ ((rb & 7) << 4)));
      }
      #pragma unroll
      for (int mi = 0; mi < 4; ++mi)
        #pragma unroll
        for (int ni = 0; ni < 4; ++ni)
          acc[mi][ni] = __builtin_amdgcn_mfma_f32_16x16x32_bf16(af[mi], bfr[ni], acc[mi][ni], 0, 0, 0);
    }
    __syncthreads();
  }
  // epilogue: scale + mask + exp -> Ps (swizzled 256B rows)
  short* Ps = &Sh[0][0];   // 128 rows x 256 B = 32 KB
  #pragma unroll
  for (int mi = 0; mi < 4; ++mi)
    #pragma unroll
    for (int r = 0; r < 4; ++r) {
      int row = wr + mi * 16 + (l4 << 2) + r;
      const float* mrow = mask + ((size_t)b * TT + m0 + row) * TT + n0;
      #pragma unroll
      for (int ni = 0; ni < 4; ++ni) {
        int col = wc + ni * 16 + l15;
        float sx = acc[mi][ni][r] * SQRTD + mrow[col];
        *(short*)((char*)Ps + ((row * 256 + col * 2) ^ ((row & 7) << 4))) = f2bf(__expf(sx));
      }
    }
  __syncthreads();
  // store pass + per-row partial sums (deterministic, from the bf16 P itself)
  #pragma unroll
  for (int c = 0; c < 8; ++c) {
    int f = c * 256 + t;
    int row = f >> 4, ch = f & 15;
    bv8 v = *(const bv8*)((const char*)Ps + ((row * 256 + ch * 16) ^ ((row & 7) << 4)));
    *(bv8*)(Pq + ((size_t)b * TT + m0 + row) * TT + n0 + ch * 8) = v;
    float s8 = 0.f;
    #pragma unroll
    for (int e = 0; e < 8; ++e) s8 += bf2f(v[e]);
    s8 += __shfl_xor(s8, 1);
    s8 += __shfl_xor(s8, 2);
    s8 += __shfl_xor(s8, 4);
    s8 += __shfl_xor(s8, 8);
    if (ch == 0)
      Lpart[(size_t)ky * (BB * TT) + (size_t)b * TT + m0 + row] = s8;
  }
}

// ---------------- K3: O = (P @ Vt^T) / l.  Tile 128x128, K = 2048.
// P/Vt staged via global_load_lds; l from Lpart (summed once into LDS).
__global__ __launch_bounds__(256, 3) void k_pv(
    const short* __restrict__ P, const short* __restrict__ Vt,
    const float* __restrict__ Lpart, float* __restrict__ Out)
{
  __shared__ __align__(16) short At[128 * 64];
  __shared__ __align__(16) short Bt[128 * 64];
  __shared__ float Lrow[128];
  const int b = blockIdx.z;
  const int m0 = blockIdx.x * 128;
  const int n0 = blockIdx.y * 128;
  const int t = threadIdx.x;
  const int lane = t & 63;
  const int w = t >> 6;
  const int wr = (w >> 1) * 64, wc = (w & 1) * 64;
  const int l15 = lane & 15, l4 = lane >> 4;
  if (t < 128) {
    float s = 0.f;
    #pragma unroll
    for (int ky = 0; ky < 16; ++ky)
      s += Lpart[(size_t)ky * (BB * TT) + (size_t)b * TT + m0 + t];
    Lrow[t] = s;
  }
  fv4 acc[4][4] = {};
  for (int kt = 0; kt < TT; kt += 64) {
    #pragma unroll
    for (int j = 0; j < 4; ++j) {
      int f = j * 256 + t;
      int row = f >> 3, c8 = f & 7;
      int srcc = (c8 ^ (row & 7)) << 3;
      gld_lds16(P + ((size_t)b * TT + m0 + row) * TT + kt + srcc, (char*)At + (size_t)f * 16);
      gld_lds16(Vt + ((size_t)b * DD + n0 + row) * TT + kt + srcc, (char*)Bt + (size_t)f * 16);
    }
    __syncthreads();
    #pragma unroll
    for (int ks = 0; ks < 2; ++ks) {
      bv8 af[4], bfr[4];
      #pragma unroll
      for (int i = 0; i < 4; ++i) {
        int ra = wr + i * 16 + l15;
        af[i] = *(bv8*)((char*)At + ((ra * 128 + ks * 64 + (l4 * 16)) ^ ((ra & 7) << 4)));
        int rb = wc + i * 16 + l15;
        bfr[i] = *(bv8*)((char*)Bt + ((rb * 128 + ks * 64 + (l4 * 16)) ^ ((rb & 7) << 4)));
      }
      #pragma unroll
      for (int mi = 0; mi < 4; ++mi)
        #pragma unroll
        for (int ni = 0; ni < 4; ++ni)
          acc[mi][ni] = __builtin_amdgcn_mfma_f32_16x16x32_bf16(af[mi], bfr[ni], acc[mi][ni], 0, 0, 0);
    }
    __syncthreads();
  }
  #pragma unroll
  for (int mi = 0; mi < 4; ++mi)
    #pragma unroll
    for (int r = 0; r < 4; ++r) {
      int ml = wr + mi * 16 + (l4 << 2) + r;
      int gm = m0 + ml;
      float inv = 1.0f / Lrow[ml];
      #pragma unroll
      for (int ni = 0; ni < 4; ++ni) {
        int gn = n0 + wc + ni * 16 + l15;
        Out[((size_t)b * TT + gm) * DD + gn] = acc[mi][ni][r] * inv;
      }
    }
}

extern "C" void kernel_launch(void* const* d_in, const int* in_sizes, int n_in,
                              void* d_out, int out_size, void* d_ws, size_t ws_size,
                              hipStream_t stream) {
  const float* ft_q = (const float*)d_in[0];
  const float* ft_k = (const float*)d_in[1];
  const float* ft_v = (const float*)d_in[2];
  const float* mask = (const float*)d_in[3];
  const float* Wq   = (const float*)d_in[4];
  const float* Wk   = (const float*)d_in[5];
  const float* Wv   = (const float*)d_in[6];
  float* Out = (float*)d_out;

  const size_t nBTD = (size_t)BB * TT * DD;   // 8,388,608
  const size_t nBTT = (size_t)BB * TT * TT;   // 33,554,432
  short* Qb = (short*)d_ws;
  short* Kb = Qb + nBTD;
  short* Vt = Kb + nBTD;
  short* Pq = Vt + nBTD;
  short* Wb = Pq + nBTT;                      // 3 x 512 x 512 bf16
  float* Lpart = (float*)(Wb + (size_t)3 * DD * DD);  // [16][B*T]

  k_castw<<<dim3(DD * DD / 8 / 256, 3), 256, 0, stream>>>(Wq, Wk, Wv, Wb);
  k_proj2<<<dim3(TT * BB / 128, DD / 256, 3), 512, 0, stream>>>(ft_q, ft_k, ft_v, Wb, Qb, Kb, Vt);
  k_sgemm<<<dim3(TT / 128, TT / 128, BB), 256, 0, stream>>>(Qb, Kb, mask, Pq, Lpart);
  k_pv<<<dim3(TT / 128, DD / 128, BB), 256, 0, stream>>>(Pq, Vt, Lpart, Out);
}